// Round 19
// baseline (172.956 us; speedup 1.0000x reference)
//
#include <hip/hip_runtime.h>
#include <math.h>

#define BATCH 4
#define NPTS 4096
#define KNBR 16
#define HDIM 128

typedef __attribute__((ext_vector_type(8))) short bf16x8;
typedef __attribute__((ext_vector_type(4))) float f32x4;
typedef unsigned long long u64;

// ws layout: [0,1MB): knn idx (int).
// [1MB, +320KB): phase A = ctab (float4, 256KB, used by knn);
//                phase B = frag-packed split weights (ushort, 320KB, used by mlp).
// Safe because stream order is: prep_points -> knn -> prep_weights -> mlp.
#define WSOFF_W (1u << 20)
#define WC_HI 0
#define WC_LO 16384
#define WN_HI 32768
#define WN_LO 49152
#define WO1_HI 65536
#define WO1_LO 98304
#define WO2_HI 131072
#define WO2_LO 147456

// branchless gelu: 0.5x(1+erf(x/sqrt2)), erf via A&S 7.1.26 (|err|<=1.5e-7)
__device__ __forceinline__ float gelu_f(float x) {
    const float z = x * 0.7071067811865476f;
    const float u = fabsf(z);
    const float z2 = z * z;
    const float t = __builtin_amdgcn_rcpf(fmaf(0.3275911f, u, 1.0f));
    const float E = __expf(-z2);
    float p = fmaf(t, 1.061405429f, -1.453152027f);
    p = fmaf(t, p, 1.421413741f);
    p = fmaf(t, p, -0.284496736f);
    p = fmaf(t, p, 0.254829592f);
    p = p * t;
    const float e = fmaf(-p, E, 1.0f);      // erf(|z|)
    const float hx = 0.5f * x;
    return fmaf(fabsf(hx), e, hx);
}

__device__ __forceinline__ void bsplit(float x, short& hi, short& lo) {
    const unsigned u = __float_as_uint(x);
    hi = (short)(u >> 16);
    const float r = x - __uint_as_float(u & 0xffff0000u);
    lo = (short)(__float_as_uint(r) >> 16);
}

__device__ __forceinline__ u64 umin64(u64 a, u64 b) { return a < b ? a : b; }
__device__ __forceinline__ u64 umax64(u64 a, u64 b) { return a > b ? a : b; }

__device__ __forceinline__ u64 readlane_u64(u64 v, int src) {
    const unsigned lo = (unsigned)__builtin_amdgcn_readlane((int)(unsigned)v, src);
    const unsigned hi = (unsigned)__builtin_amdgcn_readlane((int)(unsigned)(v >> 32), src);
    return ((u64)hi << 32) | lo;
}

// ---------------- candidate table: (x,y,z,|p|^2) ----------------
__global__ __launch_bounds__(256) void prep_points(const float* __restrict__ pts,
                                                   float4* __restrict__ ctab) {
    const int e = blockIdx.x * 256 + threadIdx.x;     // 0..16383
    const float* __restrict__ p = pts + (size_t)e * 6;
    const float x = p[0], y = p[1], z = p[2];
    const float sq = x * x + y * y + z * z;
    ctab[e] = make_float4(x, y, z, sq);
}

// ---------------- weight transpose + hi/lo split, MFMA-fragment-packed ----------------
// layout per table: frag[(ks*8 + ct)*64 + lane][8]; lane holds B[k][col] with
// col=(lane&15)+16*ct, k=ks*32+(lane>>4)*8+j  -> wave loads are 1KB contiguous.
__global__ __launch_bounds__(256) void prep_weights(
    const float* __restrict__ Wc2, const float* __restrict__ Wn2,
    const float* __restrict__ Wo1, const float* __restrict__ Wo2,
    unsigned short* __restrict__ wbuf)
{
    const int e = blockIdx.x * 256 + threadIdx.x;   // 0..81919
    const float* src;
    unsigned short *dh, *dl;
    int idx;
    if (e < 16384)      { src = Wc2; dh = wbuf + WC_HI;  dl = wbuf + WC_LO;  idx = e; }
    else if (e < 32768) { src = Wn2; dh = wbuf + WN_HI;  dl = wbuf + WN_LO;  idx = e - 16384; }
    else if (e < 65536) { src = Wo1; dh = wbuf + WO1_HI; dl = wbuf + WO1_LO; idx = e - 32768; }
    else                { src = Wo2; dh = wbuf + WO2_HI; dl = wbuf + WO2_LO; idx = e - 65536; }
    const int j = idx & 7;
    const int l = (idx >> 3) & 63;
    const int tile = idx >> 9;
    const int ct = tile & 7;
    const int ks = tile >> 3;
    const int n = (l & 15) + 16 * ct;
    const int k = ks * 32 + ((l >> 4) << 3) + j;
    const float x = src[k * 128 + n];          // src is [K][128] row-major
    short hi, lo;
    bsplit(x, hi, lo);
    dh[idx] = (unsigned short)hi;
    dl[idx] = (unsigned short)lo;
}

// ---------------- KNN v9: FOUR queries per wave ----------------
// Lanes 0..15 / 16..31 / 32..47 / 48..63 hold the 4 running top-16s. Each
// candidate chunk load serves 4 queries -> chip-wide loads halve vs v7.
// Per-query algorithm (keys, bitonic chunk-0 init, hi-word-pruned sorted
// insert with re-prune) is byte-identical to the r16/r18-proven v7 ->
// bitwise-identical neighbor sets.
__global__ __launch_bounds__(256) void knn_kernel(const float4* __restrict__ ctab,
                                                  int* __restrict__ idx_out) {
    const int wq = blockIdx.x * 4 + (threadIdx.x >> 6);   // wave id 0..4095
    const int n0 = (wq * 4) & (NPTS - 1);
    const int b = (wq * 4) >> 12;
    const int lane = threadIdx.x & 63;
    const float4* __restrict__ cb = ctab + (size_t)b * NPTS;

    const float4 q0 = cb[n0];
    const float4 q1 = cb[n0 + 1];
    const float4 q2 = cb[n0 + 2];
    const float4 q3 = cb[n0 + 3];

    auto make_keys = [&](int m, u64& k0, u64& k1, u64& k2, u64& k3) {
        const float4 cc = cb[m];
        const float d0 = q0.x * cc.x + q0.y * cc.y + q0.z * cc.z;
        const float d1 = q1.x * cc.x + q1.y * cc.y + q1.z * cc.z;
        const float d2 = q2.x * cc.x + q2.y * cc.y + q2.z * cc.z;
        const float d3 = q3.x * cc.x + q3.y * cc.y + q3.z * cc.z;
        const float e0 = fmaxf((q0.w + cc.w) - 2.0f * d0, 0.0f);
        const float e1 = fmaxf((q1.w + cc.w) - 2.0f * d1, 0.0f);
        const float e2 = fmaxf((q2.w + cc.w) - 2.0f * d2, 0.0f);
        const float e3 = fmaxf((q3.w + cc.w) - 2.0f * d3, 0.0f);
        k0 = ((u64)__float_as_uint(e0) << 32) | (unsigned)m;
        k1 = ((u64)__float_as_uint(e1) << 32) | (unsigned)m;
        k2 = ((u64)__float_as_uint(e2) << 32) | (unsigned)m;
        k3 = ((u64)__float_as_uint(e3) << 32) | (unsigned)m;
        if (m == n0)     k0 = ~0ull;
        if (m == n0 + 1) k1 = ~0ull;
        if (m == n0 + 2) k2 = ~0ull;
        if (m == n0 + 3) k3 = ~0ull;
    };

    // ---- chunk 0: exact top-16 per query via 4 cross-lane bitonic sorts ----
    u64 v0, v1, v2, v3;
    make_keys(lane, v0, v1, v2, v3);
#pragma unroll
    for (int k = 2; k <= 64; k <<= 1) {
#pragma unroll
        for (int j = k >> 1; j > 0; j >>= 1) {
            const u64 p0 = __shfl_xor(v0, j, 64);
            const u64 p1 = __shfl_xor(v1, j, 64);
            const u64 p2 = __shfl_xor(v2, j, 64);
            const u64 p3 = __shfl_xor(v3, j, 64);
            const bool keepmin = (((lane & j) == 0) == ((lane & k) == 0));
            v0 = keepmin ? umin64(v0, p0) : umax64(v0, p0);
            v1 = keepmin ? umin64(v1, p1) : umax64(v1, p1);
            v2 = keepmin ? umin64(v2, p2) : umax64(v2, p2);
            v3 = keepmin ? umin64(v3, p3) : umax64(v3, p3);
        }
    }
    // place each query's ascending top-16 into its lane group
    const u64 t1 = __shfl(v1, lane & 15, 64);
    const u64 t2 = __shfl(v2, lane & 15, 64);
    const u64 t3 = __shfl(v3, lane & 15, 64);
    u64 run = (lane < 16) ? v0 : ((lane < 32) ? t1 : ((lane < 48) ? t2 : t3));
    unsigned max0h = (unsigned)__builtin_amdgcn_readlane((int)(unsigned)(run >> 32), 15);
    unsigned max1h = (unsigned)__builtin_amdgcn_readlane((int)(unsigned)(run >> 32), 31);
    unsigned max2h = (unsigned)__builtin_amdgcn_readlane((int)(unsigned)(run >> 32), 47);
    unsigned max3h = (unsigned)__builtin_amdgcn_readlane((int)(unsigned)(run >> 32), 63);

    // exact sorted-insert of key (wave-uniform source lanes) into group g,
    // hi-word prune with re-prune (v7-proven)
    auto insert_all = [&](u64 key, int g, int rank, unsigned& maxh) {
        u64 mask = __ballot((unsigned)(key >> 32) <= maxh);
        while (mask) {
            const int src = (int)__builtin_ctzll(mask);
            const u64 K = readlane_u64(key, src);
            u64 prev = __shfl_up(run, 1, 64);
            if ((lane & 15) == 0) prev = 0;
            const u64 cand = (run < K) ? run : ((prev < K) ? K : prev);
            if ((lane >> 4) == g) run = cand;
            maxh = (unsigned)__builtin_amdgcn_readlane((int)(unsigned)(run >> 32), rank);
            mask &= mask - 1;
            mask &= __ballot((unsigned)(key >> 32) <= maxh);
        }
    };

    int c = 1;
    for (; c + 1 < NPTS / 64; c += 2) {
        const int mA = lane + 64 * c;
        const int mB = mA + 64;
        u64 a0, a1, a2, a3, b0k, b1k, b2k, b3k;
        make_keys(mA, a0, a1, a2, a3);    // two loads + dist chains overlap
        make_keys(mB, b0k, b1k, b2k, b3k);
        insert_all(a0, 0, 15, max0h);
        insert_all(a1, 1, 31, max1h);
        insert_all(a2, 2, 47, max2h);
        insert_all(a3, 3, 63, max3h);
        insert_all(b0k, 0, 15, max0h);
        insert_all(b1k, 1, 31, max1h);
        insert_all(b2k, 2, 47, max2h);
        insert_all(b3k, 3, 63, max3h);
    }
    // tail chunk (c = 63)
    {
        const int m = lane + 64 * c;
        u64 k0, k1, k2, k3;
        make_keys(m, k0, k1, k2, k3);
        insert_all(k0, 0, 15, max0h);
        insert_all(k1, 1, 31, max1h);
        insert_all(k2, 2, 47, max2h);
        insert_all(k3, 3, 63, max3h);
    }

    // all 64 lanes write: lane group g -> query n0+g, slot lane&15
    idx_out[((size_t)b * NPTS + n0 + (lane >> 4)) * KNBR + (lane & 15)] =
        (int)(run & 0xffffffffull);
}

// ---------------- branch compute v3 (r12-exact) + setprio around MFMA cluster ----------------
// NOTE: do NOT stage B through LDS here — two attempts (r9, r11) produced
// ~4-5e-3 numerical corruption with an index-verified pure copy; root cause
// not found. Global per-ct streaming is the proven-correct transport.
template<int NIN>
__device__ __forceinline__ void branch_compute(
    const float (* __restrict__ inp)[4],           // 128 rows x 4 (LDS)
    const float* __restrict__ w1s,                 // LDS [NIN][128]
    const float* __restrict__ b1s,
    const float* __restrict__ b2s,
    const unsigned short* __restrict__ w2hi,       // frag-packed [32 tiles][64][8]
    const unsigned short* __restrict__ w2lo,
    unsigned short (* __restrict__ catH)[264],
    unsigned short (* __restrict__ catL)[264],
    int colbase, int w, int l)
{
    const int lr = l & 15;
    const int lq = l >> 4;
    const int kb = lq * 8;

    f32x4 acc[2][8];
#pragma unroll
    for (int rt = 0; rt < 2; ++rt)
#pragma unroll
        for (int ct = 0; ct < 8; ++ct)
            acc[rt][ct] = (f32x4){0.f, 0.f, 0.f, 0.f};

    for (int ks = 0; ks < 4; ++ks) {
        const int c0 = ks * 32 + kb;
        // layer-1 + gelu + split: A-fragments for this K-step (gelu once/elem)
        float wr[NIN][8], bb[8];
#pragma unroll
        for (int d = 0; d < NIN; ++d) {
            *(float4*)&wr[d][0] = *(const float4*)(w1s + (d << 7) + c0);
            *(float4*)&wr[d][4] = *(const float4*)(w1s + (d << 7) + c0 + 4);
        }
        *(float4*)&bb[0] = *(const float4*)(b1s + c0);
        *(float4*)&bb[4] = *(const float4*)(b1s + c0 + 4);

        bf16x8 ah[2], al[2];
#pragma unroll
        for (int rt = 0; rt < 2; ++rt) {
            const int row = 32 * w + 16 * rt + lr;
            const float4 rv = *(const float4*)&inp[row][0];
#pragma unroll
            for (int jj = 0; jj < 8; ++jj) {
                float x = bb[jj] + rv.x * wr[0][jj] + rv.y * wr[1][jj] + rv.z * wr[2][jj];
                if (NIN == 4) x += rv.w * wr[3][jj];
                x = gelu_f(x);
                short hi, lo;
                bsplit(x, hi, lo);
                ah[rt][jj] = hi;
                al[rt][jj] = lo;
            }
        }
        // MFMA: stream B per col-tile (2 loads then 6 MFMAs); prio-boosted (T5:
        // waves of independent blocks are phase-diverse -> -1.7us measured r17).
        __builtin_amdgcn_s_setprio(1);
#pragma unroll
        for (int ct = 0; ct < 8; ++ct) {
            const size_t off = ((size_t)((ks * 8 + ct) * 64 + l)) * 8;
            const bf16x8 bh = *(const bf16x8*)(w2hi + off);
            const bf16x8 bl = *(const bf16x8*)(w2lo + off);
#pragma unroll
            for (int rt = 0; rt < 2; ++rt) {
                acc[rt][ct] = __builtin_amdgcn_mfma_f32_16x16x32_bf16(ah[rt], bh, acc[rt][ct], 0, 0, 0);
                acc[rt][ct] = __builtin_amdgcn_mfma_f32_16x16x32_bf16(ah[rt], bl, acc[rt][ct], 0, 0, 0);
                acc[rt][ct] = __builtin_amdgcn_mfma_f32_16x16x32_bf16(al[rt], bh, acc[rt][ct], 0, 0, 0);
            }
        }
        __builtin_amdgcn_s_setprio(0);
    }
    // k-max over 16 neighbors + bias + split to cat
#pragma unroll
    for (int rt = 0; rt < 2; ++rt) {
        const int p = 2 * w + rt;
#pragma unroll
        for (int ct = 0; ct < 8; ++ct) {
            const f32x4 a = acc[rt][ct];
            float m = fmaxf(fmaxf(a[0], a[1]), fmaxf(a[2], a[3]));
            m = fmaxf(m, __shfl_xor(m, 16));
            m = fmaxf(m, __shfl_xor(m, 32));
            const int col = lr + 16 * ct;
            const float v = m + b2s[col];
            if (lq == 0) {
                short hi, lo;
                bsplit(v, hi, lo);
                catH[p][colbase + col] = (unsigned short)hi;
                catL[p][colbase + col] = (unsigned short)lo;
            }
        }
    }
}

// ---------------- fused MLP with MFMA: one block (256 thr) per 8 points ----------------
// NOTE: (256,3) is final: acc[2][8] = 64 AGPRs; every 128-reg-cap attempt
// (r6/r7/r15) spilled ~72MB/dispatch to scratch.
__global__ __launch_bounds__(256, 3) void mlp_mfma(
    const float* __restrict__ pts, const int* __restrict__ knn_idx,
    const float* __restrict__ Wc1, const float* __restrict__ bc1,
    const float* __restrict__ bc2,
    const float* __restrict__ Wn1, const float* __restrict__ bn1,
    const float* __restrict__ bn2,
    const float* __restrict__ bo1, const float* __restrict__ bo2,
    const unsigned short* __restrict__ wbuf,
    float* __restrict__ outp)
{
    __shared__ __align__(16) float rel[128][4];
    __shared__ __align__(16) float nin[128][4];
    __shared__ float qpt[8][6];
    __shared__ __align__(16) unsigned short catH[8][264];
    __shared__ __align__(16) unsigned short catL[8][264];
    __shared__ __align__(16) unsigned short o1H[8][136];
    __shared__ __align__(16) unsigned short o1L[8][136];
    __shared__ __align__(16) float w1c[3 * 128];
    __shared__ __align__(16) float w1n[4 * 128];
    __shared__ __align__(16) float b1c[128], b2c[128], b1n[128], b2n[128], bo1s[128], bo2s[128];

    const int t = threadIdx.x;
    const int w = t >> 6;
    const int l = t & 63;
    const int lr = l & 15;
    const int lq = l >> 4;
    const int kb = lq * 8;
    const int blk = blockIdx.x;
    const int b = blk >> 9;                 // 512 blocks per batch
    const int n0 = (blk & 511) * 8;
    const float* __restrict__ base = pts + (size_t)b * NPTS * 6;

    // stage weights/biases
    for (int i = t; i < 384; i += 256) w1c[i] = Wc1[i];
    for (int i = t; i < 512; i += 256) w1n[i] = Wn1[i];
    if (t < 128) {
        b1c[t] = bc1[t]; b2c[t] = bc2[t];
        b1n[t] = bn1[t]; b2n[t] = bn2[t];
        bo1s[t] = bo1[t]; bo2s[t] = bo2[t];
    }
    if (t < 48) qpt[t / 6][t % 6] = base[(size_t)(n0 + t / 6) * 6 + (t % 6)];
    __syncthreads();
    if (t < 128) {
        const int p = t >> 4;
        const int m = knn_idx[((size_t)b * NPTS + n0 + p) * KNBR + (t & 15)];
        const float cx = base[(size_t)m * 6 + 0];
        const float cy = base[(size_t)m * 6 + 1];
        const float cz = base[(size_t)m * 6 + 2];
        const float nx = base[(size_t)m * 6 + 3];
        const float ny = base[(size_t)m * 6 + 4];
        const float nz = base[(size_t)m * 6 + 5];
        rel[t][0] = cx - qpt[p][0];
        rel[t][1] = cy - qpt[p][1];
        rel[t][2] = cz - qpt[p][2];
        rel[t][3] = 0.0f;
        nin[t][0] = nx; nin[t][1] = ny; nin[t][2] = nz;
        nin[t][3] = 1.0f - (qpt[p][3] * nx + qpt[p][4] * ny + qpt[p][5] * nz);
    }
    __syncthreads();

    branch_compute<3>(rel, w1c, b1c, b2c, wbuf + WC_HI, wbuf + WC_LO,
                      catH, catL, 0, w, l);
    branch_compute<4>(nin, w1n, b1n, b2n, wbuf + WN_HI, wbuf + WN_LO,
                      catH, catL, 128, w, l);
    __syncthreads();

    // ---- output MLP layer 1: M=8 pts, wave w -> col tiles 2w, 2w+1; K=256 (8 ks)
    {
        f32x4 a1[2];
        a1[0] = (f32x4){0.f, 0.f, 0.f, 0.f};
        a1[1] = (f32x4){0.f, 0.f, 0.f, 0.f};
        __builtin_amdgcn_s_setprio(1);
#pragma unroll
        for (int ks = 0; ks < 8; ++ks) {
            const int c0 = ks * 32 + kb;
            const bf16x8 ah = *(const bf16x8*)&catH[lr & 7][c0];
            const bf16x8 al = *(const bf16x8*)&catL[lr & 7][c0];
#pragma unroll
            for (int c2 = 0; c2 < 2; ++c2) {
                const int ct = 2 * w + c2;
                const unsigned short* wp = wbuf + WO1_HI + ((size_t)((ks * 8 + ct) * 64 + l)) * 8;
                const bf16x8 bh = *(const bf16x8*)wp;
                const bf16x8 bl = *(const bf16x8*)(wp + (WO1_LO - WO1_HI));
                a1[c2] = __builtin_amdgcn_mfma_f32_16x16x32_bf16(ah, bh, a1[c2], 0, 0, 0);
                a1[c2] = __builtin_amdgcn_mfma_f32_16x16x32_bf16(ah, bl, a1[c2], 0, 0, 0);
                a1[c2] = __builtin_amdgcn_mfma_f32_16x16x32_bf16(al, bh, a1[c2], 0, 0, 0);
            }
        }
        __builtin_amdgcn_s_setprio(0);
#pragma unroll
        for (int c2 = 0; c2 < 2; ++c2) {
            const int col = lr + 16 * (2 * w + c2);
            const float bo = bo1s[col];
#pragma unroll
            for (int r = 0; r < 4; ++r) {
                const int prow = lq * 4 + r;
                if (prow < 8) {
                    const float x = gelu_f(a1[c2][r] + bo);
                    short hi, lo;
                    bsplit(x, hi, lo);
                    o1H[prow][col] = (unsigned short)hi;
                    o1L[prow][col] = (unsigned short)lo;
                }
            }
        }
    }
    __syncthreads();
    // ---- output MLP layer 2: M=8, K=128 (4 ks)
    {
        f32x4 a2[2];
        a2[0] = (f32x4){0.f, 0.f, 0.f, 0.f};
        a2[1] = (f32x4){0.f, 0.f, 0.f, 0.f};
        __builtin_amdgcn_s_setprio(1);
#pragma unroll
        for (int ks = 0; ks < 4; ++ks) {
            const int c0 = ks * 32 + kb;
            const bf16x8 ah = *(const bf16x8*)&o1H[lr & 7][c0];
            const bf16x8 al = *(const bf16x8*)&o1L[lr & 7][c0];
#pragma unroll
            for (int c2 = 0; c2 < 2; ++c2) {
                const int ct = 2 * w + c2;
                const unsigned short* wp = wbuf + WO2_HI + ((size_t)((ks * 8 + ct) * 64 + l)) * 8;
                const bf16x8 bh = *(const bf16x8*)wp;
                const bf16x8 bl = *(const bf16x8*)(wp + (WO2_LO - WO2_HI));
                a2[c2] = __builtin_amdgcn_mfma_f32_16x16x32_bf16(ah, bh, a2[c2], 0, 0, 0);
                a2[c2] = __builtin_amdgcn_mfma_f32_16x16x32_bf16(ah, bl, a2[c2], 0, 0, 0);
                a2[c2] = __builtin_amdgcn_mfma_f32_16x16x32_bf16(al, bh, a2[c2], 0, 0, 0);
            }
        }
        __builtin_amdgcn_s_setprio(0);
#pragma unroll
        for (int c2 = 0; c2 < 2; ++c2) {
            const int col = lr + 16 * (2 * w + c2);
            const float bo = bo2s[col];
#pragma unroll
            for (int r = 0; r < 4; ++r) {
                const int prow = lq * 4 + r;
                if (prow < 8)
                    outp[((size_t)b * NPTS + n0 + prow) * HDIM + col] = a2[c2][r] + bo;
            }
        }
    }
}

extern "C" void kernel_launch(void* const* d_in, const int* in_sizes, int n_in,
                              void* d_out, int out_size, void* d_ws, size_t ws_size,
                              hipStream_t stream) {
    const float* pts = (const float*)d_in[0];
    const float* Wc1 = (const float*)d_in[1];
    const float* bc1 = (const float*)d_in[2];
    const float* Wc2 = (const float*)d_in[3];
    const float* bc2 = (const float*)d_in[4];
    const float* Wn1 = (const float*)d_in[5];
    const float* bn1 = (const float*)d_in[6];
    const float* Wn2 = (const float*)d_in[7];
    const float* bn2 = (const float*)d_in[8];
    const float* Wo1 = (const float*)d_in[9];
    const float* bo1 = (const float*)d_in[10];
    const float* Wo2 = (const float*)d_in[11];
    const float* bo2 = (const float*)d_in[12];
    float* outp = (float*)d_out;
    int* idx = (int*)d_ws;
    float4* ctab = (float4*)((char*)d_ws + WSOFF_W);            // phase A
    unsigned short* wbuf = (unsigned short*)((char*)d_ws + WSOFF_W);  // phase B (after knn)

    prep_points<<<dim3(BATCH * NPTS / 256), dim3(256), 0, stream>>>(pts, ctab);
    knn_kernel<<<dim3(BATCH * NPTS / 16), dim3(256), 0, stream>>>(ctab, idx);
    prep_weights<<<dim3(320), dim3(256), 0, stream>>>(Wc2, Wn2, Wo1, Wo2, wbuf);
    mlp_mfma<<<dim3(BATCH * NPTS / 8), dim3(256), 0, stream>>>(
        pts, idx, Wc1, bc1, bc2, Wn1, bn1, bn2, bo1, bo2, wbuf, outp);
}

// Round 20
// 164.017 us; speedup vs baseline: 1.0545x; 1.0545x over previous
//
#include <hip/hip_runtime.h>
#include <math.h>

#define BATCH 4
#define NPTS 4096
#define KNBR 16
#define HDIM 128

typedef __attribute__((ext_vector_type(8))) short bf16x8;
typedef __attribute__((ext_vector_type(4))) float f32x4;
typedef unsigned long long u64;

// ws layout: [0,1MB): knn idx (int).
// [1MB, +320KB): phase A = ctab (float4, 256KB, used by knn);
//                phase B = frag-packed split weights (ushort, 320KB, used by mlp).
// Safe because stream order is: prep_points -> knn -> prep_weights -> mlp.
#define WSOFF_W (1u << 20)
#define WC_HI 0
#define WC_LO 16384
#define WN_HI 32768
#define WN_LO 49152
#define WO1_HI 65536
#define WO1_LO 98304
#define WO2_HI 131072
#define WO2_LO 147456

// branchless gelu: 0.5x(1+erf(x/sqrt2)), erf via A&S 7.1.26 (|err|<=1.5e-7)
__device__ __forceinline__ float gelu_f(float x) {
    const float z = x * 0.7071067811865476f;
    const float u = fabsf(z);
    const float z2 = z * z;
    const float t = __builtin_amdgcn_rcpf(fmaf(0.3275911f, u, 1.0f));
    const float E = __expf(-z2);
    float p = fmaf(t, 1.061405429f, -1.453152027f);
    p = fmaf(t, p, 1.421413741f);
    p = fmaf(t, p, -0.284496736f);
    p = fmaf(t, p, 0.254829592f);
    p = p * t;
    const float e = fmaf(-p, E, 1.0f);      // erf(|z|)
    const float hx = 0.5f * x;
    return fmaf(fabsf(hx), e, hx);
}

__device__ __forceinline__ void bsplit(float x, short& hi, short& lo) {
    const unsigned u = __float_as_uint(x);
    hi = (short)(u >> 16);
    const float r = x - __uint_as_float(u & 0xffff0000u);
    lo = (short)(__float_as_uint(r) >> 16);
}

__device__ __forceinline__ u64 umin64(u64 a, u64 b) { return a < b ? a : b; }
__device__ __forceinline__ u64 umax64(u64 a, u64 b) { return a > b ? a : b; }

__device__ __forceinline__ u64 readlane_u64(u64 v, int src) {
    const unsigned lo = (unsigned)__builtin_amdgcn_readlane((int)(unsigned)v, src);
    const unsigned hi = (unsigned)__builtin_amdgcn_readlane((int)(unsigned)(v >> 32), src);
    return ((u64)hi << 32) | lo;
}

// ---------------- candidate table: (x,y,z,|p|^2) ----------------
__global__ __launch_bounds__(256) void prep_points(const float* __restrict__ pts,
                                                   float4* __restrict__ ctab) {
    const int e = blockIdx.x * 256 + threadIdx.x;     // 0..16383
    const float* __restrict__ p = pts + (size_t)e * 6;
    const float x = p[0], y = p[1], z = p[2];
    const float sq = x * x + y * y + z * z;
    ctab[e] = make_float4(x, y, z, sq);
}

// ---------------- weight transpose + hi/lo split, MFMA-fragment-packed ----------------
// layout per table: frag[(ks*8 + ct)*64 + lane][8]; lane holds B[k][col] with
// col=(lane&15)+16*ct, k=ks*32+(lane>>4)*8+j  -> wave loads are 1KB contiguous.
__global__ __launch_bounds__(256) void prep_weights(
    const float* __restrict__ Wc2, const float* __restrict__ Wn2,
    const float* __restrict__ Wo1, const float* __restrict__ Wo2,
    unsigned short* __restrict__ wbuf)
{
    const int e = blockIdx.x * 256 + threadIdx.x;   // 0..81919
    const float* src;
    unsigned short *dh, *dl;
    int idx;
    if (e < 16384)      { src = Wc2; dh = wbuf + WC_HI;  dl = wbuf + WC_LO;  idx = e; }
    else if (e < 32768) { src = Wn2; dh = wbuf + WN_HI;  dl = wbuf + WN_LO;  idx = e - 16384; }
    else if (e < 65536) { src = Wo1; dh = wbuf + WO1_HI; dl = wbuf + WO1_LO; idx = e - 32768; }
    else                { src = Wo2; dh = wbuf + WO2_HI; dl = wbuf + WO2_LO; idx = e - 65536; }
    const int j = idx & 7;
    const int l = (idx >> 3) & 63;
    const int tile = idx >> 9;
    const int ct = tile & 7;
    const int ks = tile >> 3;
    const int n = (l & 15) + 16 * ct;
    const int k = ks * 32 + ((l >> 4) << 3) + j;
    const float x = src[k * 128 + n];          // src is [K][128] row-major
    short hi, lo;
    bsplit(x, hi, lo);
    dh[idx] = (unsigned short)hi;
    dl[idx] = (unsigned short)lo;
}

// ---------------- KNN v7 (r18-exact): bitonic chunk-0 init + hi-word-pruned insert ----------------
// Family optimum: 1q/wave=80us, 2q/wave=55us, 4q/wave=64us (r19 — serial
// insert chains quadruple while loads only halve). 2q/wave is final.
__global__ __launch_bounds__(256) void knn_kernel(const float4* __restrict__ ctab,
                                                  int* __restrict__ idx_out) {
    const int wq = blockIdx.x * 4 + (threadIdx.x >> 6);   // wave id 0..8191
    const int n0 = (wq * 2) & (NPTS - 1);
    const int n1 = n0 + 1;
    const int b = (wq * 2) >> 12;
    const int lane = threadIdx.x & 63;
    const float4* __restrict__ cb = ctab + (size_t)b * NPTS;

    const float4 q0 = cb[n0];
    const float4 q1 = cb[n1];

    // ---- chunk 0: exact top-16 per query via cross-lane bitonic sort ----
    u64 v0, v1;
    {
        const int m = lane;
        const float4 cc = cb[m];
        const float d0 = q0.x * cc.x + q0.y * cc.y + q0.z * cc.z;
        const float d1 = q1.x * cc.x + q1.y * cc.y + q1.z * cc.z;
        const float e0 = fmaxf((q0.w + cc.w) - 2.0f * d0, 0.0f);
        const float e1 = fmaxf((q1.w + cc.w) - 2.0f * d1, 0.0f);
        v0 = ((u64)__float_as_uint(e0) << 32) | (unsigned)m;
        v1 = ((u64)__float_as_uint(e1) << 32) | (unsigned)m;
        if (m == n0) v0 = ~0ull;
        if (m == n1) v1 = ~0ull;
#pragma unroll
        for (int k = 2; k <= 64; k <<= 1) {
#pragma unroll
            for (int j = k >> 1; j > 0; j >>= 1) {
                const u64 p0 = __shfl_xor(v0, j, 64);
                const u64 p1 = __shfl_xor(v1, j, 64);
                const bool keepmin = (((lane & j) == 0) == ((lane & k) == 0));
                v0 = keepmin ? umin64(v0, p0) : umax64(v0, p0);
                v1 = keepmin ? umin64(v1, p1) : umax64(v1, p1);
            }
        }
    }
    // q0's ascending top-16 sits in lanes 0..15 of v0; move q1's into lanes 16..31.
    const u64 t1 = __shfl(v1, lane & 15, 64);
    u64 run = (lane < 16) ? v0 : ((lane < 32) ? t1 : ~0ull);
    unsigned max0h = (unsigned)__builtin_amdgcn_readlane((int)(unsigned)(run >> 32), 15);
    unsigned max1h = (unsigned)__builtin_amdgcn_readlane((int)(unsigned)(run >> 32), 31);

    // exact sorted-insert of key (wave-uniform source lanes) into group g
    auto insert_all = [&](u64 key, int g, int rank, unsigned& maxh) {
        u64 mask = __ballot((unsigned)(key >> 32) <= maxh);
        while (mask) {
            const int src = (int)__builtin_ctzll(mask);
            const u64 K = readlane_u64(key, src);
            u64 prev = __shfl_up(run, 1, 64);
            if ((lane & 15) == 0) prev = 0;
            const u64 cand = (run < K) ? run : ((prev < K) ? K : prev);
            if ((lane >> 4) == g) run = cand;
            maxh = (unsigned)__builtin_amdgcn_readlane((int)(unsigned)(run >> 32), rank);
            mask &= mask - 1;
            mask &= __ballot((unsigned)(key >> 32) <= maxh);
        }
    };

    auto make_keys = [&](int m, u64& k0, u64& k1) {
        const float4 cc = cb[m];
        const float d0 = q0.x * cc.x + q0.y * cc.y + q0.z * cc.z;
        const float d1 = q1.x * cc.x + q1.y * cc.y + q1.z * cc.z;
        const float e0 = fmaxf((q0.w + cc.w) - 2.0f * d0, 0.0f);
        const float e1 = fmaxf((q1.w + cc.w) - 2.0f * d1, 0.0f);
        k0 = ((u64)__float_as_uint(e0) << 32) | (unsigned)m;
        k1 = ((u64)__float_as_uint(e1) << 32) | (unsigned)m;
        if (m == n0) k0 = ~0ull;
        if (m == n1) k1 = ~0ull;
    };

    int c = 1;
    for (; c + 1 < NPTS / 64; c += 2) {
        const int mA = lane + 64 * c;
        const int mB = mA + 64;
        u64 a0, a1, b0k, b1k;
        make_keys(mA, a0, a1);            // two loads + dist chains overlap
        make_keys(mB, b0k, b1k);
        insert_all(a0, 0, 15, max0h);
        insert_all(a1, 1, 31, max1h);
        insert_all(b0k, 0, 15, max0h);
        insert_all(b1k, 1, 31, max1h);
    }
    // tail chunk (c = 63)
    {
        const int m = lane + 64 * c;
        u64 k0, k1;
        make_keys(m, k0, k1);
        insert_all(k0, 0, 15, max0h);
        insert_all(k1, 1, 31, max1h);
    }

    if (lane < KNBR)
        idx_out[((size_t)b * NPTS + n0) * KNBR + lane] = (int)(run & 0xffffffffull);
    else if (lane < 2 * KNBR)
        idx_out[((size_t)b * NPTS + n1) * KNBR + (lane - KNBR)] = (int)(run & 0xffffffffull);
}

// ---------------- branch compute v3 (r12-exact) + setprio around MFMA cluster ----------------
// NOTE: do NOT stage B through LDS here — two attempts (r9, r11) produced
// ~4-5e-3 numerical corruption with an index-verified pure copy; root cause
// not found. Global per-ct streaming is the proven-correct transport.
template<int NIN>
__device__ __forceinline__ void branch_compute(
    const float (* __restrict__ inp)[4],           // 128 rows x 4 (LDS)
    const float* __restrict__ w1s,                 // LDS [NIN][128]
    const float* __restrict__ b1s,
    const float* __restrict__ b2s,
    const unsigned short* __restrict__ w2hi,       // frag-packed [32 tiles][64][8]
    const unsigned short* __restrict__ w2lo,
    unsigned short (* __restrict__ catH)[264],
    unsigned short (* __restrict__ catL)[264],
    int colbase, int w, int l)
{
    const int lr = l & 15;
    const int lq = l >> 4;
    const int kb = lq * 8;

    f32x4 acc[2][8];
#pragma unroll
    for (int rt = 0; rt < 2; ++rt)
#pragma unroll
        for (int ct = 0; ct < 8; ++ct)
            acc[rt][ct] = (f32x4){0.f, 0.f, 0.f, 0.f};

    for (int ks = 0; ks < 4; ++ks) {
        const int c0 = ks * 32 + kb;
        // layer-1 + gelu + split: A-fragments for this K-step (gelu once/elem)
        float wr[NIN][8], bb[8];
#pragma unroll
        for (int d = 0; d < NIN; ++d) {
            *(float4*)&wr[d][0] = *(const float4*)(w1s + (d << 7) + c0);
            *(float4*)&wr[d][4] = *(const float4*)(w1s + (d << 7) + c0 + 4);
        }
        *(float4*)&bb[0] = *(const float4*)(b1s + c0);
        *(float4*)&bb[4] = *(const float4*)(b1s + c0 + 4);

        bf16x8 ah[2], al[2];
#pragma unroll
        for (int rt = 0; rt < 2; ++rt) {
            const int row = 32 * w + 16 * rt + lr;
            const float4 rv = *(const float4*)&inp[row][0];
#pragma unroll
            for (int jj = 0; jj < 8; ++jj) {
                float x = bb[jj] + rv.x * wr[0][jj] + rv.y * wr[1][jj] + rv.z * wr[2][jj];
                if (NIN == 4) x += rv.w * wr[3][jj];
                x = gelu_f(x);
                short hi, lo;
                bsplit(x, hi, lo);
                ah[rt][jj] = hi;
                al[rt][jj] = lo;
            }
        }
        // MFMA: stream B per col-tile (2 loads then 6 MFMAs); prio-boosted (T5:
        // waves of independent blocks are phase-diverse -> -1.7us measured r17).
        __builtin_amdgcn_s_setprio(1);
#pragma unroll
        for (int ct = 0; ct < 8; ++ct) {
            const size_t off = ((size_t)((ks * 8 + ct) * 64 + l)) * 8;
            const bf16x8 bh = *(const bf16x8*)(w2hi + off);
            const bf16x8 bl = *(const bf16x8*)(w2lo + off);
#pragma unroll
            for (int rt = 0; rt < 2; ++rt) {
                acc[rt][ct] = __builtin_amdgcn_mfma_f32_16x16x32_bf16(ah[rt], bh, acc[rt][ct], 0, 0, 0);
                acc[rt][ct] = __builtin_amdgcn_mfma_f32_16x16x32_bf16(ah[rt], bl, acc[rt][ct], 0, 0, 0);
                acc[rt][ct] = __builtin_amdgcn_mfma_f32_16x16x32_bf16(al[rt], bh, acc[rt][ct], 0, 0, 0);
            }
        }
        __builtin_amdgcn_s_setprio(0);
    }
    // k-max over 16 neighbors + bias + split to cat
#pragma unroll
    for (int rt = 0; rt < 2; ++rt) {
        const int p = 2 * w + rt;
#pragma unroll
        for (int ct = 0; ct < 8; ++ct) {
            const f32x4 a = acc[rt][ct];
            float m = fmaxf(fmaxf(a[0], a[1]), fmaxf(a[2], a[3]));
            m = fmaxf(m, __shfl_xor(m, 16));
            m = fmaxf(m, __shfl_xor(m, 32));
            const int col = lr + 16 * ct;
            const float v = m + b2s[col];
            if (lq == 0) {
                short hi, lo;
                bsplit(v, hi, lo);
                catH[p][colbase + col] = (unsigned short)hi;
                catL[p][colbase + col] = (unsigned short)lo;
            }
        }
    }
}

// ---------------- fused MLP with MFMA: one block (256 thr) per 8 points ----------------
// NOTE: (256,3) is final: acc[2][8] = 64 AGPRs; every 128-reg-cap attempt
// (r6/r7/r15) spilled ~72MB/dispatch to scratch.
__global__ __launch_bounds__(256, 3) void mlp_mfma(
    const float* __restrict__ pts, const int* __restrict__ knn_idx,
    const float* __restrict__ Wc1, const float* __restrict__ bc1,
    const float* __restrict__ bc2,
    const float* __restrict__ Wn1, const float* __restrict__ bn1,
    const float* __restrict__ bn2,
    const float* __restrict__ bo1, const float* __restrict__ bo2,
    const unsigned short* __restrict__ wbuf,
    float* __restrict__ outp)
{
    __shared__ __align__(16) float rel[128][4];
    __shared__ __align__(16) float nin[128][4];
    __shared__ float qpt[8][6];
    __shared__ __align__(16) unsigned short catH[8][264];
    __shared__ __align__(16) unsigned short catL[8][264];
    __shared__ __align__(16) unsigned short o1H[8][136];
    __shared__ __align__(16) unsigned short o1L[8][136];
    __shared__ __align__(16) float w1c[3 * 128];
    __shared__ __align__(16) float w1n[4 * 128];
    __shared__ __align__(16) float b1c[128], b2c[128], b1n[128], b2n[128], bo1s[128], bo2s[128];

    const int t = threadIdx.x;
    const int w = t >> 6;
    const int l = t & 63;
    const int lr = l & 15;
    const int lq = l >> 4;
    const int kb = lq * 8;
    const int blk = blockIdx.x;
    const int b = blk >> 9;                 // 512 blocks per batch
    const int n0 = (blk & 511) * 8;
    const float* __restrict__ base = pts + (size_t)b * NPTS * 6;

    // stage weights/biases
    for (int i = t; i < 384; i += 256) w1c[i] = Wc1[i];
    for (int i = t; i < 512; i += 256) w1n[i] = Wn1[i];
    if (t < 128) {
        b1c[t] = bc1[t]; b2c[t] = bc2[t];
        b1n[t] = bn1[t]; b2n[t] = bn2[t];
        bo1s[t] = bo1[t]; bo2s[t] = bo2[t];
    }
    if (t < 48) qpt[t / 6][t % 6] = base[(size_t)(n0 + t / 6) * 6 + (t % 6)];
    __syncthreads();
    if (t < 128) {
        const int p = t >> 4;
        const int m = knn_idx[((size_t)b * NPTS + n0 + p) * KNBR + (t & 15)];
        const float cx = base[(size_t)m * 6 + 0];
        const float cy = base[(size_t)m * 6 + 1];
        const float cz = base[(size_t)m * 6 + 2];
        const float nx = base[(size_t)m * 6 + 3];
        const float ny = base[(size_t)m * 6 + 4];
        const float nz = base[(size_t)m * 6 + 5];
        rel[t][0] = cx - qpt[p][0];
        rel[t][1] = cy - qpt[p][1];
        rel[t][2] = cz - qpt[p][2];
        rel[t][3] = 0.0f;
        nin[t][0] = nx; nin[t][1] = ny; nin[t][2] = nz;
        nin[t][3] = 1.0f - (qpt[p][3] * nx + qpt[p][4] * ny + qpt[p][5] * nz);
    }
    __syncthreads();

    branch_compute<3>(rel, w1c, b1c, b2c, wbuf + WC_HI, wbuf + WC_LO,
                      catH, catL, 0, w, l);
    branch_compute<4>(nin, w1n, b1n, b2n, wbuf + WN_HI, wbuf + WN_LO,
                      catH, catL, 128, w, l);
    __syncthreads();

    // ---- output MLP layer 1: M=8 pts, wave w -> col tiles 2w, 2w+1; K=256 (8 ks)
    {
        f32x4 a1[2];
        a1[0] = (f32x4){0.f, 0.f, 0.f, 0.f};
        a1[1] = (f32x4){0.f, 0.f, 0.f, 0.f};
        __builtin_amdgcn_s_setprio(1);
#pragma unroll
        for (int ks = 0; ks < 8; ++ks) {
            const int c0 = ks * 32 + kb;
            const bf16x8 ah = *(const bf16x8*)&catH[lr & 7][c0];
            const bf16x8 al = *(const bf16x8*)&catL[lr & 7][c0];
#pragma unroll
            for (int c2 = 0; c2 < 2; ++c2) {
                const int ct = 2 * w + c2;
                const unsigned short* wp = wbuf + WO1_HI + ((size_t)((ks * 8 + ct) * 64 + l)) * 8;
                const bf16x8 bh = *(const bf16x8*)wp;
                const bf16x8 bl = *(const bf16x8*)(wp + (WO1_LO - WO1_HI));
                a1[c2] = __builtin_amdgcn_mfma_f32_16x16x32_bf16(ah, bh, a1[c2], 0, 0, 0);
                a1[c2] = __builtin_amdgcn_mfma_f32_16x16x32_bf16(ah, bl, a1[c2], 0, 0, 0);
                a1[c2] = __builtin_amdgcn_mfma_f32_16x16x32_bf16(al, bh, a1[c2], 0, 0, 0);
            }
        }
        __builtin_amdgcn_s_setprio(0);
#pragma unroll
        for (int c2 = 0; c2 < 2; ++c2) {
            const int col = lr + 16 * (2 * w + c2);
            const float bo = bo1s[col];
#pragma unroll
            for (int r = 0; r < 4; ++r) {
                const int prow = lq * 4 + r;
                if (prow < 8) {
                    const float x = gelu_f(a1[c2][r] + bo);
                    short hi, lo;
                    bsplit(x, hi, lo);
                    o1H[prow][col] = (unsigned short)hi;
                    o1L[prow][col] = (unsigned short)lo;
                }
            }
        }
    }
    __syncthreads();
    // ---- output MLP layer 2: M=8, K=128 (4 ks)
    {
        f32x4 a2[2];
        a2[0] = (f32x4){0.f, 0.f, 0.f, 0.f};
        a2[1] = (f32x4){0.f, 0.f, 0.f, 0.f};
        __builtin_amdgcn_s_setprio(1);
#pragma unroll
        for (int ks = 0; ks < 4; ++ks) {
            const int c0 = ks * 32 + kb;
            const bf16x8 ah = *(const bf16x8*)&o1H[lr & 7][c0];
            const bf16x8 al = *(const bf16x8*)&o1L[lr & 7][c0];
#pragma unroll
            for (int c2 = 0; c2 < 2; ++c2) {
                const int ct = 2 * w + c2;
                const unsigned short* wp = wbuf + WO2_HI + ((size_t)((ks * 8 + ct) * 64 + l)) * 8;
                const bf16x8 bh = *(const bf16x8*)wp;
                const bf16x8 bl = *(const bf16x8*)(wp + (WO2_LO - WO2_HI));
                a2[c2] = __builtin_amdgcn_mfma_f32_16x16x32_bf16(ah, bh, a2[c2], 0, 0, 0);
                a2[c2] = __builtin_amdgcn_mfma_f32_16x16x32_bf16(ah, bl, a2[c2], 0, 0, 0);
                a2[c2] = __builtin_amdgcn_mfma_f32_16x16x32_bf16(al, bh, a2[c2], 0, 0, 0);
            }
        }
        __builtin_amdgcn_s_setprio(0);
#pragma unroll
        for (int c2 = 0; c2 < 2; ++c2) {
            const int col = lr + 16 * (2 * w + c2);
            const float bo = bo2s[col];
#pragma unroll
            for (int r = 0; r < 4; ++r) {
                const int prow = lq * 4 + r;
                if (prow < 8)
                    outp[((size_t)b * NPTS + n0 + prow) * HDIM + col] = a2[c2][r] + bo;
            }
        }
    }
}

extern "C" void kernel_launch(void* const* d_in, const int* in_sizes, int n_in,
                              void* d_out, int out_size, void* d_ws, size_t ws_size,
                              hipStream_t stream) {
    const float* pts = (const float*)d_in[0];
    const float* Wc1 = (const float*)d_in[1];
    const float* bc1 = (const float*)d_in[2];
    const float* Wc2 = (const float*)d_in[3];
    const float* bc2 = (const float*)d_in[4];
    const float* Wn1 = (const float*)d_in[5];
    const float* bn1 = (const float*)d_in[6];
    const float* Wn2 = (const float*)d_in[7];
    const float* bn2 = (const float*)d_in[8];
    const float* Wo1 = (const float*)d_in[9];
    const float* bo1 = (const float*)d_in[10];
    const float* Wo2 = (const float*)d_in[11];
    const float* bo2 = (const float*)d_in[12];
    float* outp = (float*)d_out;
    int* idx = (int*)d_ws;
    float4* ctab = (float4*)((char*)d_ws + WSOFF_W);            // phase A
    unsigned short* wbuf = (unsigned short*)((char*)d_ws + WSOFF_W);  // phase B (after knn)

    prep_points<<<dim3(BATCH * NPTS / 256), dim3(256), 0, stream>>>(pts, ctab);
    knn_kernel<<<dim3(BATCH * NPTS / 8), dim3(256), 0, stream>>>(ctab, idx);
    prep_weights<<<dim3(320), dim3(256), 0, stream>>>(Wc2, Wn2, Wo1, Wo2, wbuf);
    mlp_mfma<<<dim3(BATCH * NPTS / 8), dim3(256), 0, stream>>>(
        pts, idx, Wc1, bc1, bc2, Wn1, bn1, bn2, bo1, bo2, wbuf, outp);
}